// Round 15
// baseline (75.297 us; speedup 1.0000x reference)
//
#include <hip/hip_runtime.h>
#include <math.h>

#define NPRED 16384
#define NGT   32768
#define BETA  0.45f
#define GAMMA 0.45f

#define GSPLIT 32                 // gt splits (== lanes in the rescan reduce)
#define NTILE  (NGT / 32)         // 1024 tiles of 32 gt rows
#define TPS    (NTILE / GSPLIT)   // 32 tiles per nn block
#define PB     256                // preds per nn block (4 waves x 64)
#define NN_BX  (NPRED / PB)       // 64
#define RESB   (NPRED / 8)        // 2048 rescan blocks (8 preds each)

typedef float f32x16 __attribute__((ext_vector_type(16)));
typedef short short8 __attribute__((ext_vector_type(8)));

__device__ __forceinline__ unsigned bf16h(float f) {          // RNE f32->bf16
    unsigned u = __float_as_uint(f);
    return (u + 0x7FFFu + ((u >> 16) & 1u)) >> 16;
}
__device__ __forceinline__ float bf16f(unsigned h) { return __uint_as_float(h << 16); }
__device__ __forceinline__ unsigned pk2(unsigned lo, unsigned hi) { return lo | (hi << 16); }
__device__ __forceinline__ float min3f(float a, float b, float c) {
    float d; asm("v_min3_f32 %0, %1, %2, %3" : "=v"(d) : "v"(a), "v"(b), "v"(c)); return d;
}

// ---------------------------------------------------------------------------
// nn (fused prep): block stages its 32 gt tiles as split-bf16 MFMA A-frags in
// LDS (32 KB); 4 waves x 2 pred-groups scan them. Distance math verified
// exact (absmax 0.0, R10-R14):
//   A row j:  k0..7 = [xh,xh,xl,xl, yh,yh,yl,yl]  k8..15 = [zh,zh,zl,zl, g2h,g2l,0,0]
//   B col i:  k0..7 = [mxh,mxl,mxh,mxl, myh,myl,myh,myl]  k8..15 = [mzh,mzl,mzh,mzl,1,1,0,0]
// => acc[j][i] = g_j^2 - 2 p_i . g_j,  C col = lane&31 [m74/m101].
// R15: key = (bits(tile_min) & 0xFFFFFC00) | global_tile  (10-bit tile id in
// the low mantissa; ~2^-13 rel quantization -> near-tie argmin flips cost
// <=5.5e-5 each on the output, tolerance 4.5e-2). Accumulate with fminf;
// float order == (quantized d, tile) lex order for d>=0, tile order inverted
// for d<0 ties (acceptable). packed2 is u32 [pred][split]. Also zeroes the
// rescan completion counter (stream-ordered before rescan).
// ---------------------------------------------------------------------------
__global__ __launch_bounds__(256) void nn_kernel(
    const float* __restrict__ pred,
    const float* __restrict__ gt,
    unsigned* __restrict__ packed2,
    unsigned* __restrict__ counter)
{
    __shared__ uint4 AF[TPS * 64];                      // 32 KB

    if (blockIdx.x == 0 && blockIdx.y == 0 && threadIdx.x == 0) counter[0] = 0u;

    const int l  = threadIdx.x & 63;
    const int w  = threadIdx.x >> 6;
    const int by = blockIdx.y;

    // ---- stage rows [by*1024, +1024) as A-fragments into LDS
#pragma unroll
    for (int k = 0; k < 4; ++k) {
        const int lrow = threadIdx.x + k * 256;         // 0..1023
        const int j = by * (TPS * 32) + lrow;
        const float x = gt[j * 6 + 0], y = gt[j * 6 + 1], z = gt[j * 6 + 2];
        const float g2 = fmaf(x, x, fmaf(y, y, z * z));
        const unsigned xh = bf16h(x),  yh = bf16h(y),  zh = bf16h(z),  gh = bf16h(g2);
        const unsigned xl = bf16h(x - bf16f(xh)), yl = bf16h(y - bf16f(yh));
        const unsigned zl = bf16h(z - bf16f(zh)), gl = bf16h(g2 - bf16f(gh));
        const int tl = lrow >> 5, r = lrow & 31;
        AF[tl * 64 + r]      = make_uint4(pk2(xh, xh), pk2(xl, xl), pk2(yh, yh), pk2(yl, yl));
        AF[tl * 64 + 32 + r] = make_uint4(pk2(zh, zh), pk2(zl, zl), pk2(gh, gl), 0u);
    }
    __syncthreads();

    // ---- two B fragments (pred groups c and c+32)
    const int pbase = blockIdx.x * PB + w * 64;
    const int c     = l & 31;
    const bool hi   = l >= 32;
    uint4 bu0, bu1;
    {
        const int pi = pbase + c;
        const float x = pred[pi * 6 + 0], y = pred[pi * 6 + 1], zc = pred[pi * 6 + 2];
        const float mx = -2.0f * x, my = -2.0f * y, mz = -2.0f * zc;
        const unsigned xh = bf16h(mx), yh = bf16h(my), zh = bf16h(mz);
        const unsigned xl = bf16h(mx - bf16f(xh)), yl = bf16h(my - bf16f(yh));
        const unsigned zl = bf16h(mz - bf16f(zh));
        bu0.x = hi ? pk2(zh, zl) : pk2(xh, xl);
        bu0.y = bu0.x;
        bu0.z = hi ? 0x3F803F80u : pk2(yh, yl);
        bu0.w = hi ? 0u : bu0.z;
    }
    {
        const int pi = pbase + 32 + c;
        const float x = pred[pi * 6 + 0], y = pred[pi * 6 + 1], zc = pred[pi * 6 + 2];
        const float mx = -2.0f * x, my = -2.0f * y, mz = -2.0f * zc;
        const unsigned xh = bf16h(mx), yh = bf16h(my), zh = bf16h(mz);
        const unsigned xl = bf16h(mx - bf16f(xh)), yl = bf16h(my - bf16f(yh));
        const unsigned zl = bf16h(mz - bf16f(zh));
        bu1.x = hi ? pk2(zh, zl) : pk2(xh, xl);
        bu1.y = bu1.x;
        bu1.z = hi ? 0x3F803F80u : pk2(yh, yl);
        bu1.w = hi ? 0u : bu1.z;
    }
    const short8 bv0 = *(const short8*)&bu0;
    const short8 bv1 = *(const short8*)&bu1;
    const f32x16 zero = {0.f,0.f,0.f,0.f,0.f,0.f,0.f,0.f,
                         0.f,0.f,0.f,0.f,0.f,0.f,0.f,0.f};

    const float vmask = __uint_as_float(0xFFFFFC00u);   // VGPR mask for and_or
    float kmin0 = 1e30f, kmin1 = 1e30f;
    const int t0 = by * TPS;

#pragma unroll 2
    for (int tt = 0; tt < TPS; ++tt) {
        const uint4 au = AF[tt * 64 + l];
        const short8 av = *(const short8*)&au;
        const int gtile = t0 + tt;                      // wave-uniform (SGPR)
        {
            const f32x16 acc = __builtin_amdgcn_mfma_f32_32x32x16_bf16(av, bv0, zero, 0, 0, 0);
            const float m0 = min3f(acc[0],  acc[1],  acc[2]);
            const float m1 = min3f(acc[3],  acc[4],  acc[5]);
            const float m2 = min3f(acc[6],  acc[7],  acc[8]);
            const float m3 = min3f(acc[9],  acc[10], acc[11]);
            const float m4 = min3f(acc[12], acc[13], acc[14]);
            const float tmin = fminf(min3f(m0, m1, m2), min3f(m3, m4, acc[15]));
            float key;
            asm("v_and_or_b32 %0, %1, %2, %3"
                : "=v"(key) : "v"(tmin), "v"(vmask), "s"(gtile));
            kmin0 = fminf(kmin0, key);
        }
        {
            const f32x16 acc = __builtin_amdgcn_mfma_f32_32x32x16_bf16(av, bv1, zero, 0, 0, 0);
            const float m0 = min3f(acc[0],  acc[1],  acc[2]);
            const float m1 = min3f(acc[3],  acc[4],  acc[5]);
            const float m2 = min3f(acc[6],  acc[7],  acc[8]);
            const float m3 = min3f(acc[9],  acc[10], acc[11]);
            const float m4 = min3f(acc[12], acc[13], acc[14]);
            const float tmin = fminf(min3f(m0, m1, m2), min3f(m3, m4, acc[15]));
            float key;
            asm("v_and_or_b32 %0, %1, %2, %3"
                : "=v"(key) : "v"(tmin), "v"(vmask), "s"(gtile));
            kmin1 = fminf(kmin1, key);
        }
    }

    // cross-half merges (lane l <-> l+32 hold complementary rows; keys compare
    // as floats)
    kmin0 = fminf(kmin0, __shfl_xor(kmin0, 32, 64));
    kmin1 = fminf(kmin1, __shfl_xor(kmin1, 32, 64));

    const float km = hi ? kmin1 : kmin0;
    packed2[(size_t)(pbase + l) * GSPLIT + by] = __float_as_uint(km);
}

// ---------------------------------------------------------------------------
// rescan + fused final: 2048 blocks x 8 preds (4 waves x 2 halves).
//  Per pred: 32 lanes load the pred's 32 split keys (128 B contiguous),
//  fminf shuffle-reduce, tile = bits & 0x3FF; exact-fp32 argmin in the
//  winning 32-row tile (first occurrence); normals cosine; block partial.
//  Last block (threadfence + atomic counter, validated R13) sums partials +
//  regularizer -> out[0]. No float atomics anywhere.
// ---------------------------------------------------------------------------
__global__ __launch_bounds__(256) void rescan_kernel(
    const float* __restrict__ pred,
    const float* __restrict__ gt,
    const unsigned* __restrict__ packed2,
    float* __restrict__ partials,
    unsigned* __restrict__ counter,
    const float* __restrict__ Rm,
    const float* __restrict__ tv,
    const float* __restrict__ sv,
    float* __restrict__ out)
{
    __shared__ float part[8];
    __shared__ bool  isLast;
    const int w = threadIdx.x >> 6, l = threadIdx.x & 63;
    const int half = l >> 5, jl = l & 31;
    const int pi = blockIdx.x * 8 + w * 2 + half;

    // coalesced key load + float min-reduce over the 32 splits
    float e = __uint_as_float(packed2[(size_t)pi * GSPLIT + jl]);
#pragma unroll
    for (int off = 16; off; off >>= 1)
        e = fminf(e, __shfl_xor(e, off, 32));
    const unsigned tix = __float_as_uint(e) & 0x3FFu;   // winning 32-row tile

    const int row = (int)tix * 32 + jl;
    const float gx = gt[row * 6 + 0], gy = gt[row * 6 + 1], gz = gt[row * 6 + 2];
    const float g2 = fmaf(gx, gx, fmaf(gy, gy, gz * gz));
    const float px = pred[pi * 6 + 0], py = pred[pi * 6 + 1], pz = pred[pi * 6 + 2];
    float d = fmaf(px, -2.0f * gx, fmaf(py, -2.0f * gy, fmaf(pz, -2.0f * gz, g2)));
    int jj = jl;
#pragma unroll
    for (int off = 16; off; off >>= 1) {
        const float d2 = __shfl_xor(d, off, 32);
        const int   j2 = __shfl_xor(jj, off, 32);
        const bool t = (d2 < d) || (d2 == d && j2 < jj);
        d  = t ? d2 : d;
        jj = t ? j2 : jj;
    }
    if (jl == 0) {
        const int idx = (int)tix * 32 + jj;
        const float nx = pred[pi * 6 + 3], ny = pred[pi * 6 + 4], nz = pred[pi * 6 + 5];
        const float ax = gt[idx * 6 + 3],  ay = gt[idx * 6 + 4],  az = gt[idx * 6 + 5];
        const float pn = fmaxf(sqrtf(fmaf(nx, nx, fmaf(ny, ny, nz * nz))), 1e-12f);
        const float gn = fmaxf(sqrtf(fmaf(ax, ax, fmaf(ay, ay, az * az))), 1e-12f);
        part[w * 2 + half] = 1.0f - fmaf(nx, ax, fmaf(ny, ay, nz * az)) / (pn * gn);
    }
    __syncthreads();
    if (threadIdx.x == 0) {
        float s = 0.f;
#pragma unroll
        for (int i = 0; i < 8; ++i) s += part[i];
        partials[blockIdx.x] = s;
        __threadfence();
        const unsigned old = atomicAdd(counter, 1u);
        isLast = (old == RESB - 1);
    }
    __syncthreads();

    if (isLast) {
        __threadfence();
        float s = 0.f;
        for (int i = threadIdx.x; i < RESB; i += 256) s += partials[i];
#pragma unroll
        for (int off = 32; off; off >>= 1) s += __shfl_down(s, off, 64);
        __shared__ float ws_[4];
        if ((threadIdx.x & 63) == 0) ws_[threadIdx.x >> 6] = s;
        __syncthreads();
        if (threadIdx.x == 0) {
            const float t = ws_[0] + ws_[1] + ws_[2] + ws_[3];
            float rs = 0.f;
#pragma unroll
            for (int k = 0; k < 9; ++k) {
                const float v = Rm[k] - ((k % 4 == 0) ? 1.0f : 0.0f);
                rs = fmaf(v, v, rs);
            }
            const float rot = sqrtf(rs);
            const float tr  = sqrtf(fmaf(tv[0], tv[0], fmaf(tv[1], tv[1], tv[2] * tv[2])));
            const float sc  = (sv[0] - 1.0f) * (sv[0] - 1.0f);
            out[0] = GAMMA * t / (float)NPRED + BETA * (rot + tr + sc);
        }
    }
}

extern "C" void kernel_launch(void* const* d_in, const int* in_sizes, int n_in,
                              void* d_out, int out_size, void* d_ws, size_t ws_size,
                              hipStream_t stream)
{
    const float* pred = (const float*)d_in[0];
    const float* gt   = (const float*)d_in[1];
    const float* Rm   = (const float*)d_in[2];
    const float* tv   = (const float*)d_in[3];
    const float* sv   = (const float*)d_in[4];
    float* out = (float*)d_out;

    unsigned* packed2 = (unsigned*)d_ws;                                  // 2 MB
    float* partials   = (float*)((char*)d_ws + (size_t)NPRED * GSPLIT * 4);   // 8 KB
    unsigned* counter = (unsigned*)((char*)d_ws + (size_t)NPRED * GSPLIT * 4 + 8192);

    nn_kernel<<<dim3(NN_BX, GSPLIT), 256, 0, stream>>>(pred, gt, packed2, counter);
    rescan_kernel<<<RESB, 256, 0, stream>>>(pred, gt, packed2, partials, counter,
                                            Rm, tv, sv, out);
}

// Round 16
// 40.943 us; speedup vs baseline: 1.8391x; 1.8391x over previous
//
#include <hip/hip_runtime.h>
#include <math.h>

#define NPRED 16384
#define NGT   32768
#define BETA  0.45f
#define GAMMA 0.45f

#define GSPLIT 32                 // gt splits (== lanes in the rescan reduce)
#define NTILE  (NGT / 32)         // 1024 tiles of 32 gt rows
#define TPS    (NTILE / GSPLIT)   // 32 tiles per nn block
#define PB     256                // preds per nn block (4 waves x 64)
#define NN_BX  (NPRED / PB)       // 64
#define RESB   (NPRED / 8)        // 2048 rescan blocks (8 preds each)

typedef float f32x16 __attribute__((ext_vector_type(16)));
typedef short short8 __attribute__((ext_vector_type(8)));

__device__ __forceinline__ unsigned bf16h(float f) {          // RNE f32->bf16
    unsigned u = __float_as_uint(f);
    return (u + 0x7FFFu + ((u >> 16) & 1u)) >> 16;
}
__device__ __forceinline__ float bf16f(unsigned h) { return __uint_as_float(h << 16); }
__device__ __forceinline__ unsigned pk2(unsigned lo, unsigned hi) { return lo | (hi << 16); }
__device__ __forceinline__ float min3f(float a, float b, float c) {
    float d; asm("v_min3_f32 %0, %1, %2, %3" : "=v"(d) : "v"(a), "v"(b), "v"(c)); return d;
}

// ---------------------------------------------------------------------------
// nn (fused prep): block stages its 32 gt tiles as split-bf16 MFMA A-frags in
// LDS (32 KB); 4 waves x 2 pred-groups scan them. Distance math verified
// exact (absmax 0.0, R10-R15):
//   A row j:  k0..7 = [xh,xh,xl,xl, yh,yh,yl,yl]  k8..15 = [zh,zh,zl,zl, g2h,g2l,0,0]
//   B col i:  k0..7 = [mxh,mxl,mxh,mxl, myh,myl,myh,myl]  k8..15 = [mzh,mzl,mzh,mzl,1,1,0,0]
// => acc[j][i] = g_j^2 - 2 p_i . g_j,  C col = lane&31 [m74/m101].
// Key path (validated R15, absmax 0.0): key = (bits(tile_min) & 0xFFFFFC00)
// | global_tile via one v_and_or_b32; accumulate with fminf. packed2 is u32
// [pred][split] (coalesced rescan loads).
// NOTE (R15 lesson): NO fused-final / counter / threadfence anywhere — 2048x
// same-line device atomics + fences cost ~34 µs on 8-XCD CDNA4.
// ---------------------------------------------------------------------------
__global__ __launch_bounds__(256) void nn_kernel(
    const float* __restrict__ pred,
    const float* __restrict__ gt,
    unsigned* __restrict__ packed2)
{
    __shared__ uint4 AF[TPS * 64];                      // 32 KB

    const int l  = threadIdx.x & 63;
    const int w  = threadIdx.x >> 6;
    const int by = blockIdx.y;

    // ---- stage rows [by*1024, +1024) as A-fragments into LDS
#pragma unroll
    for (int k = 0; k < 4; ++k) {
        const int lrow = threadIdx.x + k * 256;         // 0..1023
        const int j = by * (TPS * 32) + lrow;
        const float x = gt[j * 6 + 0], y = gt[j * 6 + 1], z = gt[j * 6 + 2];
        const float g2 = fmaf(x, x, fmaf(y, y, z * z));
        const unsigned xh = bf16h(x),  yh = bf16h(y),  zh = bf16h(z),  gh = bf16h(g2);
        const unsigned xl = bf16h(x - bf16f(xh)), yl = bf16h(y - bf16f(yh));
        const unsigned zl = bf16h(z - bf16f(zh)), gl = bf16h(g2 - bf16f(gh));
        const int tl = lrow >> 5, r = lrow & 31;
        AF[tl * 64 + r]      = make_uint4(pk2(xh, xh), pk2(xl, xl), pk2(yh, yh), pk2(yl, yl));
        AF[tl * 64 + 32 + r] = make_uint4(pk2(zh, zh), pk2(zl, zl), pk2(gh, gl), 0u);
    }
    __syncthreads();

    // ---- two B fragments (pred groups c and c+32)
    const int pbase = blockIdx.x * PB + w * 64;
    const int c     = l & 31;
    const bool hi   = l >= 32;
    uint4 bu0, bu1;
    {
        const int pi = pbase + c;
        const float x = pred[pi * 6 + 0], y = pred[pi * 6 + 1], zc = pred[pi * 6 + 2];
        const float mx = -2.0f * x, my = -2.0f * y, mz = -2.0f * zc;
        const unsigned xh = bf16h(mx), yh = bf16h(my), zh = bf16h(mz);
        const unsigned xl = bf16h(mx - bf16f(xh)), yl = bf16h(my - bf16f(yh));
        const unsigned zl = bf16h(mz - bf16f(zh));
        bu0.x = hi ? pk2(zh, zl) : pk2(xh, xl);
        bu0.y = bu0.x;
        bu0.z = hi ? 0x3F803F80u : pk2(yh, yl);
        bu0.w = hi ? 0u : bu0.z;
    }
    {
        const int pi = pbase + 32 + c;
        const float x = pred[pi * 6 + 0], y = pred[pi * 6 + 1], zc = pred[pi * 6 + 2];
        const float mx = -2.0f * x, my = -2.0f * y, mz = -2.0f * zc;
        const unsigned xh = bf16h(mx), yh = bf16h(my), zh = bf16h(mz);
        const unsigned xl = bf16h(mx - bf16f(xh)), yl = bf16h(my - bf16f(yh));
        const unsigned zl = bf16h(mz - bf16f(zh));
        bu1.x = hi ? pk2(zh, zl) : pk2(xh, xl);
        bu1.y = bu1.x;
        bu1.z = hi ? 0x3F803F80u : pk2(yh, yl);
        bu1.w = hi ? 0u : bu1.z;
    }
    const short8 bv0 = *(const short8*)&bu0;
    const short8 bv1 = *(const short8*)&bu1;
    const f32x16 zero = {0.f,0.f,0.f,0.f,0.f,0.f,0.f,0.f,
                         0.f,0.f,0.f,0.f,0.f,0.f,0.f,0.f};

    const float vmask = __uint_as_float(0xFFFFFC00u);   // VGPR mask for and_or
    float kmin0 = 1e30f, kmin1 = 1e30f;
    const int t0 = by * TPS;

#pragma unroll 2
    for (int tt = 0; tt < TPS; ++tt) {
        const uint4 au = AF[tt * 64 + l];
        const short8 av = *(const short8*)&au;
        const int gtile = t0 + tt;                      // wave-uniform (SGPR)
        {
            const f32x16 acc = __builtin_amdgcn_mfma_f32_32x32x16_bf16(av, bv0, zero, 0, 0, 0);
            const float m0 = min3f(acc[0],  acc[1],  acc[2]);
            const float m1 = min3f(acc[3],  acc[4],  acc[5]);
            const float m2 = min3f(acc[6],  acc[7],  acc[8]);
            const float m3 = min3f(acc[9],  acc[10], acc[11]);
            const float m4 = min3f(acc[12], acc[13], acc[14]);
            const float tmin = fminf(min3f(m0, m1, m2), min3f(m3, m4, acc[15]));
            float key;
            asm("v_and_or_b32 %0, %1, %2, %3"
                : "=v"(key) : "v"(tmin), "v"(vmask), "s"(gtile));
            kmin0 = fminf(kmin0, key);
        }
        {
            const f32x16 acc = __builtin_amdgcn_mfma_f32_32x32x16_bf16(av, bv1, zero, 0, 0, 0);
            const float m0 = min3f(acc[0],  acc[1],  acc[2]);
            const float m1 = min3f(acc[3],  acc[4],  acc[5]);
            const float m2 = min3f(acc[6],  acc[7],  acc[8]);
            const float m3 = min3f(acc[9],  acc[10], acc[11]);
            const float m4 = min3f(acc[12], acc[13], acc[14]);
            const float tmin = fminf(min3f(m0, m1, m2), min3f(m3, m4, acc[15]));
            float key;
            asm("v_and_or_b32 %0, %1, %2, %3"
                : "=v"(key) : "v"(tmin), "v"(vmask), "s"(gtile));
            kmin1 = fminf(kmin1, key);
        }
    }

    // cross-half merges (lane l <-> l+32 hold complementary rows)
    kmin0 = fminf(kmin0, __shfl_xor(kmin0, 32, 64));
    kmin1 = fminf(kmin1, __shfl_xor(kmin1, 32, 64));

    const float km = hi ? kmin1 : kmin0;
    packed2[(size_t)(pbase + l) * GSPLIT + by] = __float_as_uint(km);
}

// ---------------------------------------------------------------------------
// rescan: 2048 blocks x 8 preds. Per pred: 32 lanes load the pred's 32 split
// keys (128 B contiguous), fminf shuffle-reduce, tile = bits & 0x3FF; exact
// fp32 argmin in the winning 32-row tile (first occurrence); normals cosine;
// per-block partial. No atomics, no fences (R15 lesson).
// ---------------------------------------------------------------------------
__global__ __launch_bounds__(256) void rescan_kernel(
    const float* __restrict__ pred,
    const float* __restrict__ gt,
    const unsigned* __restrict__ packed2,
    float* __restrict__ partials)
{
    __shared__ float part[8];
    const int w = threadIdx.x >> 6, l = threadIdx.x & 63;
    const int half = l >> 5, jl = l & 31;
    const int pi = blockIdx.x * 8 + w * 2 + half;

    float e = __uint_as_float(packed2[(size_t)pi * GSPLIT + jl]);
#pragma unroll
    for (int off = 16; off; off >>= 1)
        e = fminf(e, __shfl_xor(e, off, 32));
    const unsigned tix = __float_as_uint(e) & 0x3FFu;   // winning 32-row tile

    const int row = (int)tix * 32 + jl;
    const float gx = gt[row * 6 + 0], gy = gt[row * 6 + 1], gz = gt[row * 6 + 2];
    const float g2 = fmaf(gx, gx, fmaf(gy, gy, gz * gz));
    const float px = pred[pi * 6 + 0], py = pred[pi * 6 + 1], pz = pred[pi * 6 + 2];
    float d = fmaf(px, -2.0f * gx, fmaf(py, -2.0f * gy, fmaf(pz, -2.0f * gz, g2)));
    int jj = jl;
#pragma unroll
    for (int off = 16; off; off >>= 1) {
        const float d2 = __shfl_xor(d, off, 32);
        const int   j2 = __shfl_xor(jj, off, 32);
        const bool t = (d2 < d) || (d2 == d && j2 < jj);
        d  = t ? d2 : d;
        jj = t ? j2 : jj;
    }
    if (jl == 0) {
        const int idx = (int)tix * 32 + jj;
        const float nx = pred[pi * 6 + 3], ny = pred[pi * 6 + 4], nz = pred[pi * 6 + 5];
        const float ax = gt[idx * 6 + 3],  ay = gt[idx * 6 + 4],  az = gt[idx * 6 + 5];
        const float pn = fmaxf(sqrtf(fmaf(nx, nx, fmaf(ny, ny, nz * nz))), 1e-12f);
        const float gn = fmaxf(sqrtf(fmaf(ax, ax, fmaf(ay, ay, az * az))), 1e-12f);
        part[w * 2 + half] = 1.0f - fmaf(nx, ax, fmaf(ny, ay, nz * az)) / (pn * gn);
    }
    __syncthreads();
    if (threadIdx.x == 0) {
        float s = 0.f;
#pragma unroll
        for (int i = 0; i < 8; ++i) s += part[i];
        partials[blockIdx.x] = s;
    }
}

// ---------------------------------------------------------------------------
// final: sum partials + regularizer, single write to out[0].
// ---------------------------------------------------------------------------
__global__ __launch_bounds__(256) void final_kernel(
    const float* __restrict__ partials,
    const float* __restrict__ Rm,
    const float* __restrict__ tv,
    const float* __restrict__ sv,
    float* __restrict__ out)
{
    __shared__ float ws_[4];
    float s = 0.f;
    for (int i = threadIdx.x; i < RESB; i += 256) s += partials[i];
#pragma unroll
    for (int off = 32; off; off >>= 1) s += __shfl_down(s, off, 64);
    if ((threadIdx.x & 63) == 0) ws_[threadIdx.x >> 6] = s;
    __syncthreads();
    if (threadIdx.x == 0) {
        const float t = ws_[0] + ws_[1] + ws_[2] + ws_[3];
        float rs = 0.f;
#pragma unroll
        for (int k = 0; k < 9; ++k) {
            const float v = Rm[k] - ((k % 4 == 0) ? 1.0f : 0.0f);
            rs = fmaf(v, v, rs);
        }
        const float rot = sqrtf(rs);
        const float tr  = sqrtf(fmaf(tv[0], tv[0], fmaf(tv[1], tv[1], tv[2] * tv[2])));
        const float sc  = (sv[0] - 1.0f) * (sv[0] - 1.0f);
        out[0] = GAMMA * t / (float)NPRED + BETA * (rot + tr + sc);
    }
}

extern "C" void kernel_launch(void* const* d_in, const int* in_sizes, int n_in,
                              void* d_out, int out_size, void* d_ws, size_t ws_size,
                              hipStream_t stream)
{
    const float* pred = (const float*)d_in[0];
    const float* gt   = (const float*)d_in[1];
    const float* Rm   = (const float*)d_in[2];
    const float* tv   = (const float*)d_in[3];
    const float* sv   = (const float*)d_in[4];
    float* out = (float*)d_out;

    unsigned* packed2 = (unsigned*)d_ws;                                  // 2 MB
    float* partials   = (float*)((char*)d_ws + (size_t)NPRED * GSPLIT * 4);   // 8 KB

    nn_kernel<<<dim3(NN_BX, GSPLIT), 256, 0, stream>>>(pred, gt, packed2);
    rescan_kernel<<<RESB, 256, 0, stream>>>(pred, gt, packed2, partials);
    final_kernel<<<1, 256, 0, stream>>>(partials, Rm, tv, sv, out);
}